// Round 7
// baseline (467.641 us; speedup 1.0000x reference)
//
#include <hip/hip_runtime.h>
#include <hip/hip_bf16.h>
#include <math.h>

// Problem constants
#define Bn  4
#define Gn  2
#define Nn  2048
#define Dn  512
#define Hn  8
#define DHn 64
#define N1n 2049
#define NPAD 2112          // keys padded to 33 tiles of 64 (rows >2048 masked)
#define BGH (Bn*Gn*Hn)     // 64

// softmax scale folded with log2(e):  s' = (q.k) * 0.125 * log2e, exp2 domain
#define SCL 0.18033688011112042f

typedef short short8 __attribute__((ext_vector_type(8)));
typedef float float4v __attribute__((ext_vector_type(4)));

// Workspace byte offsets
#define OB_B  ((size_t)0)            // bf16 O  [64][2048][64]   16,777,216
#define QB_B  ((size_t)16777216)     // bf16 Q  [64][2048][64]   16,777,216
#define KB_B  ((size_t)33554432)     // bf16 K  [64][2112][64]   17,301,504
#define VT_B  ((size_t)50855936)     // bf16 V^T[64][64][2112]   17,301,504
#define XB_B  ((size_t)68157440)     // bf16 x  [4][2][2048][512] 16,777,216
#define WC_B  ((size_t)84934656)     // bf16 Wc [2][1536][512]    3,145,728
#define WO_B  ((size_t)88080384)     // bf16 Wo [2][512][512]     1,048,576
#define CSQ_B ((size_t)89128960)     // f32x2 interleaved cos/sin rot_q  1,048,576
#define CSK_B ((size_t)90177536)     // f32x2 interleaved cos/sin rot_k  1,048,576
// end = 91,226,112 B (~87 MiB)

static __device__ __forceinline__ unsigned short f2bf(float x) {
    union { float f; unsigned int u; } c; c.f = x;
    unsigned int r = c.u + 0x7fffu + ((c.u >> 16) & 1u);   // RNE
    return (unsigned short)(r >> 16);
}

// pack two floats to bf16x2 (round-half-up) in one v_perm
static __device__ __forceinline__ unsigned int pk2bf(float lo, float hi) {
    union { float f; unsigned int u; } a, b; a.f = lo; b.f = hi;
    return __builtin_amdgcn_perm(b.u + 0x8000u, a.u + 0x8000u, 0x07060302u);
}

static __device__ __forceinline__ void gload16(const void* g, void* l) {
    __builtin_amdgcn_global_load_lds(
        (const __attribute__((address_space(1))) void*)g,
        (__attribute__((address_space(3))) void*)l, 16, 0, 0);
}

// ---------------------------------------------------------------------------
// Kernel 0: prep — bf16 casts of x / Wq|Wkv / Wout, interleaved cos/sin
// tables, null-kv fill.  All segments by flat thread index.
// ---------------------------------------------------------------------------
#define S0 2097152                   // xb float4 slots  (8,388,608 floats / 4)
#define S1 393216                    // Wc  (2 * 196608)
#define S2 131072                    // Wo
#define S3 32768                     // rot_q (4 angles each)
#define S4 32768                     // rot_k
#define S5 8192                      // nulls
__global__ __launch_bounds__(256) void prep(const float* __restrict__ x,
                                            const float* __restrict__ Wq,
                                            const float* __restrict__ Wkv,
                                            const float* __restrict__ Wout,
                                            const float* __restrict__ nkv,
                                            const float* __restrict__ rot_q,
                                            const float* __restrict__ rot_k,
                                            char* __restrict__ wsb)
{
    const int idx = blockIdx.x * 256 + threadIdx.x;
    if (idx < S0) {
        float4 v = ((const float4*)x)[idx];
        ((ushort4*)(wsb + XB_B))[idx] =
            make_ushort4(f2bf(v.x), f2bf(v.y), f2bf(v.z), f2bf(v.w));
    } else if (idx < S0 + S1) {
        const int t = idx - S0;
        const int g = t / 196608;
        const int r4 = t - g * 196608;
        const int j = r4 * 4;
        const int row = j >> 9, k = j & 511;
        const float* src = (row < 512)
            ? (Wq  + ((size_t)g * 512  + row)        * 512 + k)
            : (Wkv + ((size_t)g * 1024 + (row - 512)) * 512 + k);
        float4 v = *(const float4*)src;
        ((ushort4*)(wsb + WC_B))[(size_t)g * 196608 + r4] =
            make_ushort4(f2bf(v.x), f2bf(v.y), f2bf(v.z), f2bf(v.w));
    } else if (idx < S0 + S1 + S2) {
        const int t = idx - (S0 + S1);
        float4 v = ((const float4*)Wout)[t];
        ((ushort4*)(wsb + WO_B))[t] =
            make_ushort4(f2bf(v.x), f2bf(v.y), f2bf(v.z), f2bf(v.w));
    } else if (idx < S0 + S1 + S2 + S3) {
        const int t = idx - (S0 + S1 + S2);
        float4 a = ((const float4*)rot_q)[t];
        float2* cs = (float2*)(wsb + CSQ_B);
        cs[t*4+0] = make_float2(cosf(a.x), sinf(a.x));
        cs[t*4+1] = make_float2(cosf(a.y), sinf(a.y));
        cs[t*4+2] = make_float2(cosf(a.z), sinf(a.z));
        cs[t*4+3] = make_float2(cosf(a.w), sinf(a.w));
    } else if (idx < S0 + S1 + S2 + S3 + S4) {
        const int t = idx - (S0 + S1 + S2 + S3);
        float4 a = ((const float4*)rot_k)[t];
        float2* cs = (float2*)(wsb + CSK_B);
        cs[t*4+0] = make_float2(cosf(a.x), sinf(a.x));
        cs[t*4+1] = make_float2(cosf(a.y), sinf(a.y));
        cs[t*4+2] = make_float2(cosf(a.z), sinf(a.z));
        cs[t*4+3] = make_float2(cosf(a.w), sinf(a.w));
    } else if (idx < S0 + S1 + S2 + S3 + S4 + S5) {
        const int t = idx - (S0 + S1 + S2 + S3 + S4);
        const int s = t >> 12, rem = t & 4095;
        const int bgh = rem >> 6, dh = rem & 63;
        const int gh = bgh & 15;
        if (s == 0)
            ((unsigned short*)(wsb + KB_B))[(size_t)bgh * NPAD * 64 + dh] =
                f2bf(nkv[gh * 64 + dh]);
        else
            ((unsigned short*)(wsb + VT_B))[((size_t)bgh * 64 + dh) * NPAD] =
                f2bf(nkv[1024 + gh * 64 + dh]);
    }
}
#define PREP_BLOCKS ((S0+S1+S2+S3+S4+S5)/256)

// ---------------------------------------------------------------------------
// Kernel 1: bf16 MFMA QKV projection (verified R5 structure).
// ---------------------------------------------------------------------------
__global__ __launch_bounds__(256) void qkv_proj(char* __restrict__ wsb)
{
    __shared__ alignas(16) unsigned short As[128 * 64];
    __shared__ alignas(16) unsigned short Bs[128 * 64];

    const int g  = blockIdx.z;
    const int m0 = blockIdx.x * 128;    // rows over b*N (per g)
    const int e0 = blockIdx.y * 128;    // cols over 1536
    const int tid = threadIdx.x;
    const int wv = tid >> 6, ln = tid & 63;
    const int l15 = ln & 15, quad = ln >> 4;
    const int wm = (wv & 1) * 64, we = (wv >> 1) * 64;

    const unsigned short* xb = (const unsigned short*)(wsb + XB_B);
    const unsigned short* wc = (const unsigned short*)(wsb + WC_B);

    const int bq = m0 >> 11;                          // batch (block-uniform)
    const size_t arowbase = ((size_t)(bq * Gn + g) * Nn + (m0 & 2047));
    const size_t brockbase = ((size_t)g * 1536 + e0);

    float4v acc[4][4];
    #pragma unroll
    for (int i = 0; i < 4; ++i)
        #pragma unroll
        for (int j = 0; j < 4; ++j) acc[i][j] = (float4v){0.f,0.f,0.f,0.f};

    for (int k0 = 0; k0 < 512; k0 += 64) {
        #pragma unroll
        for (int it = 0; it < 4; ++it) {
            const int sb  = it * 256 + wv * 64;       // wave-uniform slot base
            const int slot = sb + ln;
            const int row = slot >> 3;
            const int c8  = (slot & 7) ^ (row & 7);
            gload16(xb + (arowbase + row) * 512 + k0 + c8 * 8, &As[(size_t)sb * 8]);
            gload16(wc + (brockbase + row) * 512 + k0 + c8 * 8, &Bs[(size_t)sb * 8]);
        }
        __syncthreads();

        #pragma unroll
        for (int kh = 0; kh < 2; ++kh) {
            short8 af[4], bf[4];
            #pragma unroll
            for (int mi = 0; mi < 4; ++mi) {
                const int r = wm + mi * 16 + l15;
                af[mi] = *(const short8*)&As[r * 64 + (((kh*4+quad) ^ (r & 7)) << 3)];
            }
            #pragma unroll
            for (int ni = 0; ni < 4; ++ni) {
                const int r = we + ni * 16 + l15;
                bf[ni] = *(const short8*)&Bs[r * 64 + (((kh*4+quad) ^ (r & 7)) << 3)];
            }
            #pragma unroll
            for (int mi = 0; mi < 4; ++mi)
                #pragma unroll
                for (int ni = 0; ni < 4; ++ni)
                    acc[mi][ni] = __builtin_amdgcn_mfma_f32_16x16x32_bf16(
                        af[mi], bf[ni], acc[mi][ni], 0, 0, 0);
        }
        __syncthreads();
    }

    // Epilogue.  e = e0 + we + ni*16 + l15; sec uniform; h = hbase + (wv>>1).
    const int sec  = e0 >> 9;
    const int hoff = wv >> 1;
    const int nb   = (m0 & 2047) + wm;

    if (sec == 0) {
        unsigned short* Qb = (unsigned short*)(wsb + QB_B);
        const float2* cs = (const float2*)(wsb + CSQ_B);
        const int bgh = (bq * Gn + g) * Hn + ((e0 & 511) >> 6) + hoff;
        #pragma unroll
        for (int mi = 0; mi < 4; ++mi) {
            #pragma unroll
            for (int r = 0; r < 4; ++r) {
                const int n = nb + mi * 16 + quad * 4 + r;
                unsigned short* qrow = Qb + ((size_t)bgh * Nn + n) * 64;
                #pragma unroll
                for (int ni = 0; ni < 4; ++ni) {
                    const int dh = ni * 16 + l15;
                    float2 c = cs[n * 64 + dh];
                    const float v = acc[mi][ni][r];
                    const float p = acc[mi][ni ^ 2][r];
                    const float rh = (ni < 2) ? -p : p;
                    qrow[dh] = f2bf((v * c.x + rh * c.y) * SCL);
                }
            }
        }
    } else if (sec == 1) {
        unsigned short* Kb = (unsigned short*)(wsb + KB_B);
        const float2* cs = (const float2*)(wsb + CSK_B);
        const int bgh = (bq * Gn + g) * Hn + ((e0 - 512) >> 6) + hoff;
        #pragma unroll
        for (int mi = 0; mi < 4; ++mi) {
            #pragma unroll
            for (int r = 0; r < 4; ++r) {
                const int n = nb + mi * 16 + quad * 4 + r;
                unsigned short* krow = Kb + ((size_t)bgh * NPAD + n + 1) * 64;
                #pragma unroll
                for (int ni = 0; ni < 4; ++ni) {
                    const int dh = ni * 16 + l15;
                    float2 c = cs[n * 64 + dh];
                    const float v = acc[mi][ni][r];
                    const float p = acc[mi][ni ^ 2][r];
                    const float rh = (ni < 2) ? -p : p;
                    krow[dh] = f2bf(v * c.x + rh * c.y);
                }
            }
        }
    } else {
        unsigned short* Vt = (unsigned short*)(wsb + VT_B);
        const int bgh = (bq * Gn + g) * Hn + ((e0 - 1024) >> 6) + hoff;
        #pragma unroll
        for (int mi = 0; mi < 4; ++mi) {
            #pragma unroll
            for (int ni = 0; ni < 4; ++ni) {
                const int dh = ni * 16 + l15;
                unsigned short* vrow = Vt + ((size_t)bgh * 64 + dh) * NPAD
                                         + nb + mi * 16 + quad * 4 + 1;
                #pragma unroll
                for (int r = 0; r < 4; ++r)
                    vrow[r] = f2bf(acc[mi][ni][r]);
            }
        }
    }
}

// ---------------------------------------------------------------------------
// Kernel 2: bf16 MFMA flash attention v3.
//   Wave partition: qh = wv&1 (64 q), kh2 = wv>>1 (32 keys of each 64-tile).
//   Halves K-frag and V-frag LDS redundancy vs v2 (80 KB vs 112 KB per
//   block-iter).  O/l are key-partial per wave; one cross-wave LDS reduce at
//   the end (overlays Ks/Vs/Ps).  No online max (scores bounded).
// ---------------------------------------------------------------------------
__global__ __launch_bounds__(256, 4) void attn(const unsigned short* __restrict__ Qb,
                                               const unsigned short* __restrict__ Kb,
                                               const unsigned short* __restrict__ Vt,
                                               unsigned short* __restrict__ Ob)
{
    __shared__ alignas(16) char smem[33280];
    unsigned short* Ks = (unsigned short*)smem;             // [64 key][64 dh] swizzled, 8 KB
    unsigned short* Vs = (unsigned short*)(smem + 8192);    // [64 dh][64 key] swizzled, 8 KB
    unsigned short* Ps = (unsigned short*)(smem + 16384);   // 4 waves x [64 q][32 key] swizzled, 16 KB
    float*          lrb = (float*)(smem + 32768);           // [2 qh][64 q]

    const int tid  = threadIdx.x;
    const int bid  = blockIdx.x;
    const int bgh  = bid >> 4;           // 16 consecutive blocks share a head
    const int q0   = (bid & 15) * 128;
    const int wv   = tid >> 6;
    const int ln   = tid & 63;
    const int l15  = ln & 15;
    const int quad = ln >> 4;
    const int qh   = wv & 1;             // q half (64 rows)
    const int kh2  = wv >> 1;            // key half (32 keys per 64-tile)

    // Q B-frags: bq[qs][c], lane holds Q[q = q0+qh*64+qs*16+l15][c*32+quad*8+j]
    short8 bq[4][2];
    #pragma unroll
    for (int qs = 0; qs < 4; ++qs) {
        const unsigned short* qrow =
            Qb + ((size_t)bgh * Nn + q0 + qh * 64 + qs * 16 + l15) * 64;
        bq[qs][0] = *(const short8*)(qrow + quad * 8);
        bq[qs][1] = *(const short8*)(qrow + 32 + quad * 8);
    }

    float4v acc[4][4];                    // [qs][nt]: O-partial, m=q, n=dh
    #pragma unroll
    for (int qs = 0; qs < 4; ++qs)
        #pragma unroll
        for (int nt = 0; nt < 4; ++nt) acc[qs][nt] = (float4v){0.f,0.f,0.f,0.f};
    float lr[4] = {0.f, 0.f, 0.f, 0.f};   // l-partial for q = qs*16+l15

    const unsigned short* kptr = Kb + (size_t)bgh * NPAD * 64;
    const unsigned short* vptr = Vt + (size_t)bgh * 64 * NPAD;
    unsigned short* Pw = Ps + wv * 64 * 32;

    for (int kt = 0; kt <= 2048; kt += 64) {
        // stage K tile [64 key][64 dh] and V tile [64 dh][64 key]
        #pragma unroll
        for (int it = 0; it < 2; ++it) {
            const int sb  = it * 256 + wv * 64;      // wave-uniform slot base
            const int slot = sb + ln;
            const int row = slot >> 3;
            const int c8  = (slot & 7) ^ (row & 7);
            gload16(kptr + (size_t)row * 64   + c8 * 8, &Ks[(size_t)sb * 8]);
            gload16(vptr + (size_t)row * NPAD + c8 * 8, &Vs[(size_t)sb * 8]);
        }
        __syncthreads();

        // QK^T on this wave's 32 keys: S^T tiles, exp2, pack into Pw
        #pragma unroll
        for (int mt = 0; mt < 2; ++mt) {
            const int rk = kh2 * 32 + mt * 16 + l15;     // key row in tile
            short8 af0 = *(const short8*)&Ks[rk * 64 + (((    quad) ^ (rk & 7)) << 3)];
            short8 af1 = *(const short8*)&Ks[rk * 64 + (((4 + quad) ^ (rk & 7)) << 3)];
            #pragma unroll
            for (int qs = 0; qs < 4; ++qs) {
                float4v z = {0.f, 0.f, 0.f, 0.f};
                z = __builtin_amdgcn_mfma_f32_16x16x32_bf16(af0, bq[qs][0], z, 0, 0, 0);
                z = __builtin_amdgcn_mfma_f32_16x16x32_bf16(af1, bq[qs][1], z, 0, 0, 0);
                if (kt == 2048) {                        // mask pad keys (> 2048)
                    #pragma unroll
                    for (int r = 0; r < 4; ++r)
                        if (kh2 * 32 + mt * 16 + quad * 4 + r > 0) z[r] = -INFINITY;
                }
                float pv0 = __builtin_amdgcn_exp2f(z[0]);
                float pv1 = __builtin_amdgcn_exp2f(z[1]);
                float pv2 = __builtin_amdgcn_exp2f(z[2]);
                float pv3 = __builtin_amdgcn_exp2f(z[3]);
                lr[qs] += (pv0 + pv1) + (pv2 + pv3);
                uint2 w = make_uint2(pk2bf(pv0, pv1), pk2bf(pv2, pv3));
                const int rq = qs * 16 + l15;
                const int cq = mt * 2 + (quad >> 1);     // 16B chunk (4/row)
                *(uint2*)&Pw[rq * 32 + ((cq ^ (rq & 3)) << 3) + (quad & 1) * 4] = w;
            }
        }

        // PV: A = P[64 q][32 key] (own keys), B = V^T key-half rows
        short8 ap[4];
        #pragma unroll
        for (int qs = 0; qs < 4; ++qs) {
            const int rq = qs * 16 + l15;
            ap[qs] = *(const short8*)&Pw[rq * 32 + ((quad ^ (rq & 3)) << 3)];
        }
        #pragma unroll
        for (int nt = 0; nt < 4; ++nt) {
            const int rv = nt * 16 + l15;
            const int c  = kh2 * 4 + quad;               // key 16B chunk (8/row)
            short8 bv = *(const short8*)&Vs[rv * 64 + ((c ^ (rv & 7)) << 3)];
            #pragma unroll
            for (int qs = 0; qs < 4; ++qs)
                acc[qs][nt] = __builtin_amdgcn_mfma_f32_16x16x32_bf16(
                    ap[qs], bv, acc[qs][nt], 0, 0, 0);
        }
        __syncthreads();

        kptr += 64 * 64;
        vptr += 64;
    }

    // quad-reduce l partials (per q = qs*16+l15, this wave's keys)
    float lsum[4];
    #pragma unroll
    for (int qs = 0; qs < 4; ++qs) {
        float l = lr[qs];
        l += __shfl_xor(l, 16);
        l += __shfl_xor(l, 32);
        lsum[qs] = l;
    }

    // cross-wave (key-half) reduction through LDS overlay
    float* Of = (float*)smem;            // [2 qh][64 q][64 dh] fp32 = 32 KB
    if (kh2 == 1) {
        #pragma unroll
        for (int qs = 0; qs < 4; ++qs)
            #pragma unroll
            for (int r = 0; r < 4; ++r) {
                float* orow = Of + (qh * 64 + qs * 16 + quad * 4 + r) * 64;
                #pragma unroll
                for (int nt = 0; nt < 4; ++nt)
                    orow[nt * 16 + l15] = acc[qs][nt][r];
            }
        if (quad == 0) {
            #pragma unroll
            for (int qs = 0; qs < 4; ++qs)
                lrb[qh * 64 + qs * 16 + l15] = lsum[qs];
        }
    }
    __syncthreads();
    if (kh2 == 0) {
        float inv[4];
        #pragma unroll
        for (int qs = 0; qs < 4; ++qs)
            inv[qs] = 1.f / (lsum[qs] + lrb[qh * 64 + qs * 16 + l15]);
        unsigned short* obase = Ob + ((size_t)bgh * Nn + q0 + qh * 64) * 64;
        #pragma unroll
        for (int qs = 0; qs < 4; ++qs) {
            #pragma unroll
            for (int r = 0; r < 4; ++r) {
                const float iv = __shfl(inv[qs], quad * 4 + r);
                const float* orow = Of + (qh * 64 + qs * 16 + quad * 4 + r) * 64;
                #pragma unroll
                for (int nt = 0; nt < 4; ++nt)
                    obase[(qs * 16 + quad * 4 + r) * 64 + nt * 16 + l15] =
                        f2bf((acc[qs][nt][r] + orow[nt * 16 + l15]) * iv);
            }
        }
    }
}

// ---------------------------------------------------------------------------
// Kernel 3: bf16 MFMA output projection (verified R5 structure).
// ---------------------------------------------------------------------------
__global__ __launch_bounds__(256) void out_proj(const char* __restrict__ wsb,
                                                float* __restrict__ out)
{
    __shared__ alignas(16) unsigned short As[128 * 64];
    __shared__ alignas(16) unsigned short Bs[128 * 64];

    const int g  = blockIdx.z;
    const int m0 = blockIdx.x * 128;
    const int c0 = blockIdx.y * 128;
    const int tid = threadIdx.x;
    const int wv = tid >> 6, ln = tid & 63;
    const int l15 = ln & 15, quad = ln >> 4;
    const int wm = (wv & 1) * 64, we = (wv >> 1) * 64;

    const unsigned short* Ob = (const unsigned short*)(wsb + OB_B);
    const unsigned short* Wo = (const unsigned short*)(wsb + WO_B);

    const int bq = m0 >> 11;
    const int n0 = m0 & 2047;

    float4v acc[4][4];
    #pragma unroll
    for (int i = 0; i < 4; ++i)
        #pragma unroll
        for (int j = 0; j < 4; ++j) acc[i][j] = (float4v){0.f,0.f,0.f,0.f};

    for (int k0 = 0; k0 < 512; k0 += 64) {
        const int h = k0 >> 6;
        const unsigned short* abase =
            Ob + (((size_t)(bq * Gn + g) * Hn + h) * Nn + n0) * 64;
        const unsigned short* bbase =
            Wo + ((size_t)g * 512 + c0) * 512 + k0;
        #pragma unroll
        for (int it = 0; it < 4; ++it) {
            const int sb  = it * 256 + wv * 64;
            const int slot = sb + ln;
            const int row = slot >> 3;
            const int c8  = (slot & 7) ^ (row & 7);
            gload16(abase + (size_t)row * 64  + c8 * 8, &As[(size_t)sb * 8]);
            gload16(bbase + (size_t)row * 512 + c8 * 8, &Bs[(size_t)sb * 8]);
        }
        __syncthreads();

        #pragma unroll
        for (int kh = 0; kh < 2; ++kh) {
            short8 af[4], bf[4];
            #pragma unroll
            for (int mi = 0; mi < 4; ++mi) {
                const int r = wm + mi * 16 + l15;
                af[mi] = *(const short8*)&As[r * 64 + (((kh*4+quad) ^ (r & 7)) << 3)];
            }
            #pragma unroll
            for (int ni = 0; ni < 4; ++ni) {
                const int r = we + ni * 16 + l15;
                bf[ni] = *(const short8*)&Bs[r * 64 + (((kh*4+quad) ^ (r & 7)) << 3)];
            }
            #pragma unroll
            for (int mi = 0; mi < 4; ++mi)
                #pragma unroll
                for (int ni = 0; ni < 4; ++ni)
                    acc[mi][ni] = __builtin_amdgcn_mfma_f32_16x16x32_bf16(
                        af[mi], bf[ni], acc[mi][ni], 0, 0, 0);
        }
        __syncthreads();
    }

    #pragma unroll
    for (int mi = 0; mi < 4; ++mi) {
        #pragma unroll
        for (int r = 0; r < 4; ++r) {
            const int n = n0 + wm + mi * 16 + quad * 4 + r;
            float* orow = out + ((size_t)(bq * Gn + g) * Nn + n) * Dn;
            #pragma unroll
            for (int ni = 0; ni < 4; ++ni)
                orow[c0 + we + ni * 16 + l15] = acc[mi][ni][r];
        }
    }
}

// ---------------------------------------------------------------------------
extern "C" void kernel_launch(void* const* d_in, const int* in_sizes, int n_in,
                              void* d_out, int out_size, void* d_ws, size_t ws_size,
                              hipStream_t stream)
{
    const float* x     = (const float*)d_in[0];
    const float* Wq    = (const float*)d_in[1];
    const float* Wkv   = (const float*)d_in[2];
    const float* Wout  = (const float*)d_in[3];
    const float* nkv   = (const float*)d_in[4];
    const float* rot_q = (const float*)d_in[5];
    const float* rot_k = (const float*)d_in[6];
    float* out = (float*)d_out;
    char* wsb  = (char*)d_ws;   // needs ~87 MB

    prep<<<dim3(PREP_BLOCKS), 256, 0, stream>>>(x, Wq, Wkv, Wout, nkv,
                                                rot_q, rot_k, wsb);

    qkv_proj<<<dim3(64, 12, 2), 256, 0, stream>>>(wsb);

    attn<<<dim3(BGH * 16), 256, 0, stream>>>((const unsigned short*)(wsb + QB_B),
                                             (const unsigned short*)(wsb + KB_B),
                                             (const unsigned short*)(wsb + VT_B),
                                             (unsigned short*)(wsb + OB_B));

    out_proj<<<dim3(64, 4, 2), 256, 0, stream>>>(wsb, out);
}

// Round 8
// 268.722 us; speedup vs baseline: 1.7402x; 1.7402x over previous
//
#include <hip/hip_runtime.h>
#include <hip/hip_bf16.h>
#include <math.h>

// Problem constants
#define Bn  4
#define Gn  2
#define Nn  2048
#define Dn  512
#define Hn  8
#define DHn 64
#define NPAD 2112          // keys padded: real keys 0..2047, null at 2048, 2049+ masked
#define BGH (Bn*Gn*Hn)     // 64

// softmax scale folded with log2(e):  s' = (q.k) * 0.125 * log2e, exp2 domain
#define SCL 0.18033688011112042f

typedef short short8 __attribute__((ext_vector_type(8)));
typedef float float4v __attribute__((ext_vector_type(4)));

// Workspace byte offsets
#define OB_B  ((size_t)0)            // bf16 O  [64][2048][64]   16,777,216
#define QB_B  ((size_t)16777216)     // bf16 Q  [64][2048][64]   16,777,216
#define KB_B  ((size_t)33554432)     // bf16 K  [64][2112][64]   17,301,504
#define VT_B  ((size_t)50855936)     // bf16 V^T[64][64][2112]   17,301,504
#define XB_B  ((size_t)68157440)     // bf16 x  [4][2][2048][512] 16,777,216
#define WC_B  ((size_t)84934656)     // bf16 Wc [2][1536][512]    3,145,728
#define WO_B  ((size_t)88080384)     // bf16 Wo [2][512][512]     1,048,576
#define CSQ_B ((size_t)89128960)     // f32x2 interleaved cos/sin rot_q  1,048,576
#define CSK_B ((size_t)90177536)     // f32x2 interleaved cos/sin rot_k  1,048,576
// end = 91,226,112 B (~87 MiB)

static __device__ __forceinline__ unsigned short f2bf(float x) {
    union { float f; unsigned int u; } c; c.f = x;
    unsigned int r = c.u + 0x7fffu + ((c.u >> 16) & 1u);   // RNE
    return (unsigned short)(r >> 16);
}

// pack two floats to bf16x2 (round-half-up) in one v_perm
static __device__ __forceinline__ unsigned int pk2bf(float lo, float hi) {
    union { float f; unsigned int u; } a, b; a.f = lo; b.f = hi;
    return __builtin_amdgcn_perm(b.u + 0x8000u, a.u + 0x8000u, 0x07060302u);
}

static __device__ __forceinline__ void gload16(const void* g, void* l) {
    __builtin_amdgcn_global_load_lds(
        (const __attribute__((address_space(1))) void*)g,
        (__attribute__((address_space(3))) void*)l, 16, 0, 0);
}

// ---------------------------------------------------------------------------
// Kernel 0: prep — bf16 casts of x / Wq|Wkv / Wout, interleaved cos/sin
// tables, null-kv fill (at key slot 2048).  Segments by flat thread index.
// ---------------------------------------------------------------------------
#define S0 2097152                   // xb float4 slots  (8,388,608 floats / 4)
#define S1 393216                    // Wc  (2 * 196608)
#define S2 131072                    // Wo
#define S3 32768                     // rot_q (4 angles each)
#define S4 32768                     // rot_k
#define S5 8192                      // nulls
__global__ __launch_bounds__(256) void prep(const float* __restrict__ x,
                                            const float* __restrict__ Wq,
                                            const float* __restrict__ Wkv,
                                            const float* __restrict__ Wout,
                                            const float* __restrict__ nkv,
                                            const float* __restrict__ rot_q,
                                            const float* __restrict__ rot_k,
                                            char* __restrict__ wsb)
{
    const int idx = blockIdx.x * 256 + threadIdx.x;
    if (idx < S0) {
        float4 v = ((const float4*)x)[idx];
        ((ushort4*)(wsb + XB_B))[idx] =
            make_ushort4(f2bf(v.x), f2bf(v.y), f2bf(v.z), f2bf(v.w));
    } else if (idx < S0 + S1) {
        const int t = idx - S0;
        const int g = t / 196608;
        const int r4 = t - g * 196608;
        const int j = r4 * 4;
        const int row = j >> 9, k = j & 511;
        const float* src = (row < 512)
            ? (Wq  + ((size_t)g * 512  + row)        * 512 + k)
            : (Wkv + ((size_t)g * 1024 + (row - 512)) * 512 + k);
        float4 v = *(const float4*)src;
        ((ushort4*)(wsb + WC_B))[(size_t)g * 196608 + r4] =
            make_ushort4(f2bf(v.x), f2bf(v.y), f2bf(v.z), f2bf(v.w));
    } else if (idx < S0 + S1 + S2) {
        const int t = idx - (S0 + S1);
        float4 v = ((const float4*)Wout)[t];
        ((ushort4*)(wsb + WO_B))[t] =
            make_ushort4(f2bf(v.x), f2bf(v.y), f2bf(v.z), f2bf(v.w));
    } else if (idx < S0 + S1 + S2 + S3) {
        const int t = idx - (S0 + S1 + S2);
        float4 a = ((const float4*)rot_q)[t];
        float2* cs = (float2*)(wsb + CSQ_B);
        cs[t*4+0] = make_float2(cosf(a.x), sinf(a.x));
        cs[t*4+1] = make_float2(cosf(a.y), sinf(a.y));
        cs[t*4+2] = make_float2(cosf(a.z), sinf(a.z));
        cs[t*4+3] = make_float2(cosf(a.w), sinf(a.w));
    } else if (idx < S0 + S1 + S2 + S3 + S4) {
        const int t = idx - (S0 + S1 + S2 + S3);
        float4 a = ((const float4*)rot_k)[t];
        float2* cs = (float2*)(wsb + CSK_B);
        cs[t*4+0] = make_float2(cosf(a.x), sinf(a.x));
        cs[t*4+1] = make_float2(cosf(a.y), sinf(a.y));
        cs[t*4+2] = make_float2(cosf(a.z), sinf(a.z));
        cs[t*4+3] = make_float2(cosf(a.w), sinf(a.w));
    } else if (idx < S0 + S1 + S2 + S3 + S4 + S5) {
        const int t = idx - (S0 + S1 + S2 + S3 + S4);
        const int s = t >> 12, rem = t & 4095;
        const int bgh = rem >> 6, dh = rem & 63;
        const int gh = bgh & 15;
        if (s == 0)
            ((unsigned short*)(wsb + KB_B))[(size_t)bgh * NPAD * 64 + (size_t)2048 * 64 + dh] =
                f2bf(nkv[gh * 64 + dh]);
        else
            ((unsigned short*)(wsb + VT_B))[((size_t)bgh * 64 + dh) * NPAD + 2048] =
                f2bf(nkv[1024 + gh * 64 + dh]);
    }
}
#define PREP_BLOCKS ((S0+S1+S2+S3+S4+S5)/256)

// ---------------------------------------------------------------------------
// Kernel 1: bf16 MFMA QKV projection (verified R5/R6 structure).
// K rows / V^T cols now at n (null kv lives at slot 2048) -> V stores ushort4.
// ---------------------------------------------------------------------------
__global__ __launch_bounds__(256) void qkv_proj(char* __restrict__ wsb)
{
    __shared__ alignas(16) unsigned short As[128 * 64];
    __shared__ alignas(16) unsigned short Bs[128 * 64];

    const int g  = blockIdx.z;
    const int m0 = blockIdx.x * 128;    // rows over b*N (per g)
    const int e0 = blockIdx.y * 128;    // cols over 1536
    const int tid = threadIdx.x;
    const int wv = tid >> 6, ln = tid & 63;
    const int l15 = ln & 15, quad = ln >> 4;
    const int wm = (wv & 1) * 64, we = (wv >> 1) * 64;

    const unsigned short* xb = (const unsigned short*)(wsb + XB_B);
    const unsigned short* wc = (const unsigned short*)(wsb + WC_B);

    const int bq = m0 >> 11;                          // batch (block-uniform)
    const size_t arowbase = ((size_t)(bq * Gn + g) * Nn + (m0 & 2047));
    const size_t brockbase = ((size_t)g * 1536 + e0);

    float4v acc[4][4];
    #pragma unroll
    for (int i = 0; i < 4; ++i)
        #pragma unroll
        for (int j = 0; j < 4; ++j) acc[i][j] = (float4v){0.f,0.f,0.f,0.f};

    for (int k0 = 0; k0 < 512; k0 += 64) {
        #pragma unroll
        for (int it = 0; it < 4; ++it) {
            const int sb  = it * 256 + wv * 64;       // wave-uniform slot base
            const int slot = sb + ln;
            const int row = slot >> 3;
            const int c8  = (slot & 7) ^ (row & 7);
            gload16(xb + (arowbase + row) * 512 + k0 + c8 * 8, &As[(size_t)sb * 8]);
            gload16(wc + (brockbase + row) * 512 + k0 + c8 * 8, &Bs[(size_t)sb * 8]);
        }
        __syncthreads();

        #pragma unroll
        for (int kh = 0; kh < 2; ++kh) {
            short8 af[4], bf[4];
            #pragma unroll
            for (int mi = 0; mi < 4; ++mi) {
                const int r = wm + mi * 16 + l15;
                af[mi] = *(const short8*)&As[r * 64 + (((kh*4+quad) ^ (r & 7)) << 3)];
            }
            #pragma unroll
            for (int ni = 0; ni < 4; ++ni) {
                const int r = we + ni * 16 + l15;
                bf[ni] = *(const short8*)&Bs[r * 64 + (((kh*4+quad) ^ (r & 7)) << 3)];
            }
            #pragma unroll
            for (int mi = 0; mi < 4; ++mi)
                #pragma unroll
                for (int ni = 0; ni < 4; ++ni)
                    acc[mi][ni] = __builtin_amdgcn_mfma_f32_16x16x32_bf16(
                        af[mi], bf[ni], acc[mi][ni], 0, 0, 0);
        }
        __syncthreads();
    }

    // Epilogue.  e = e0 + we + ni*16 + l15; sec uniform; h = hbase + (wv>>1).
    const int sec  = e0 >> 9;
    const int hoff = wv >> 1;
    const int nb   = (m0 & 2047) + wm;

    if (sec == 0) {
        unsigned short* Qb = (unsigned short*)(wsb + QB_B);
        const float2* cs = (const float2*)(wsb + CSQ_B);
        const int bgh = (bq * Gn + g) * Hn + ((e0 & 511) >> 6) + hoff;
        #pragma unroll
        for (int mi = 0; mi < 4; ++mi) {
            #pragma unroll
            for (int r = 0; r < 4; ++r) {
                const int n = nb + mi * 16 + quad * 4 + r;
                unsigned short* qrow = Qb + ((size_t)bgh * Nn + n) * 64;
                #pragma unroll
                for (int ni = 0; ni < 4; ++ni) {
                    const int dh = ni * 16 + l15;
                    float2 c = cs[n * 64 + dh];
                    const float v = acc[mi][ni][r];
                    const float p = acc[mi][ni ^ 2][r];
                    const float rh = (ni < 2) ? -p : p;
                    qrow[dh] = f2bf((v * c.x + rh * c.y) * SCL);
                }
            }
        }
    } else if (sec == 1) {
        unsigned short* Kb = (unsigned short*)(wsb + KB_B);
        const float2* cs = (const float2*)(wsb + CSK_B);
        const int bgh = (bq * Gn + g) * Hn + ((e0 - 512) >> 6) + hoff;
        #pragma unroll
        for (int mi = 0; mi < 4; ++mi) {
            #pragma unroll
            for (int r = 0; r < 4; ++r) {
                const int n = nb + mi * 16 + quad * 4 + r;
                unsigned short* krow = Kb + ((size_t)bgh * NPAD + n) * 64;
                #pragma unroll
                for (int ni = 0; ni < 4; ++ni) {
                    const int dh = ni * 16 + l15;
                    float2 c = cs[n * 64 + dh];
                    const float v = acc[mi][ni][r];
                    const float p = acc[mi][ni ^ 2][r];
                    const float rh = (ni < 2) ? -p : p;
                    krow[dh] = f2bf(v * c.x + rh * c.y);
                }
            }
        }
    } else {
        unsigned short* Vt = (unsigned short*)(wsb + VT_B);
        const int bgh = (bq * Gn + g) * Hn + ((e0 - 1024) >> 6) + hoff;
        #pragma unroll
        for (int mi = 0; mi < 4; ++mi) {
            #pragma unroll
            for (int ni = 0; ni < 4; ++ni) {
                const int dh = ni * 16 + l15;
                unsigned short* vrow = Vt + ((size_t)bgh * 64 + dh) * NPAD
                                         + nb + mi * 16 + quad * 4;
                ushort4 w = { f2bf(acc[mi][ni][0]), f2bf(acc[mi][ni][1]),
                              f2bf(acc[mi][ni][2]), f2bf(acc[mi][ni][3]) };
                *(ushort4*)vrow = w;
            }
        }
    }
}

// ---------------------------------------------------------------------------
// Kernel 2: bf16 MFMA flash attention (verified R6 structure) + XCD swizzle.
//   4 waves x 32 q-rows = 128 q per block; 64-key tiles (33 iters).
//   XCD swizzle: all 16 q-tiles of one head share bid mod 8 -> same XCD L2.
// ---------------------------------------------------------------------------
__global__ __launch_bounds__(256, 4) void attn(const unsigned short* __restrict__ Qb,
                                               const unsigned short* __restrict__ Kb,
                                               const unsigned short* __restrict__ Vt,
                                               unsigned short* __restrict__ Ob)
{
    __shared__ alignas(16) unsigned short Ks[64 * 64];   // [key][dh]  swizzled
    __shared__ alignas(16) unsigned short Vs[64 * 64];   // [dh][key]  swizzled
    __shared__ alignas(16) unsigned short Ps[4 * 32 * 64]; // per-wave [q][key] swizzled

    const int tid  = threadIdx.x;
    const int bid  = blockIdx.x;
    const int bgh  = (bid >> 7) * 8 + (bid & 7);   // 16 q-tiles/head share bid%8
    const int q0   = ((bid >> 3) & 15) * 128;
    const int wv   = tid >> 6;
    const int ln   = tid & 63;
    const int l15  = ln & 15;
    const int quad = ln >> 4;

    // Q B-frags: bq[qs][kh], lane holds Q[q = q0+wv*32+qs*16+l15][kh*32+quad*8 ..]
    short8 bq[2][2];
    #pragma unroll
    for (int qs = 0; qs < 2; ++qs) {
        const unsigned short* qrow =
            Qb + ((size_t)bgh * Nn + q0 + wv * 32 + qs * 16 + l15) * 64;
        bq[qs][0] = *(const short8*)(qrow + quad * 8);
        bq[qs][1] = *(const short8*)(qrow + 32 + quad * 8);
    }

    float4v Oa[2][4];
    #pragma unroll
    for (int ms = 0; ms < 2; ++ms)
        #pragma unroll
        for (int nt = 0; nt < 4; ++nt) Oa[ms][nt] = (float4v){0.f,0.f,0.f,0.f};
    float lr[2] = {0.f, 0.f};

    const unsigned short* kptr = Kb + (size_t)bgh * NPAD * 64;
    const unsigned short* vptr = Vt + (size_t)bgh * 64 * NPAD;
    unsigned short* Pw = Ps + wv * 32 * 64;

    for (int kt = 0; kt <= 2048; kt += 64) {
        // stage K tile [64 keys][64 dh] and V tile [64 dh][64 keys]
        #pragma unroll
        for (int it = 0; it < 2; ++it) {
            const int sb  = it * 256 + wv * 64;      // wave-uniform slot base
            const int slot = sb + ln;
            const int row = slot >> 3;
            const int c8  = (slot & 7) ^ (row & 7);
            gload16(kptr + (size_t)row * 64   + c8 * 8, &Ks[(size_t)sb * 8]);
            gload16(vptr + (size_t)row * NPAD + c8 * 8, &Vs[(size_t)sb * 8]);
        }
        __syncthreads();

        // S^T per 16-key subtile: exp2 -> pack -> store to Pw
        #pragma unroll
        for (int mt = 0; mt < 4; ++mt) {
            const int rk = mt * 16 + l15;            // key row in tile
            short8 af0 = *(const short8*)&Ks[rk * 64 + (((    quad) ^ (rk & 7)) << 3)];
            short8 af1 = *(const short8*)&Ks[rk * 64 + (((4 + quad) ^ (rk & 7)) << 3)];
            #pragma unroll
            for (int qs = 0; qs < 2; ++qs) {
                float4v z = {0.f, 0.f, 0.f, 0.f};
                z = __builtin_amdgcn_mfma_f32_16x16x32_bf16(af0, bq[qs][0], z, 0, 0, 0);
                z = __builtin_amdgcn_mfma_f32_16x16x32_bf16(af1, bq[qs][1], z, 0, 0, 0);
                if (kt == 2048) {                    // mask pad keys (> 2048)
                    #pragma unroll
                    for (int r = 0; r < 4; ++r)
                        if (mt * 16 + quad * 4 + r > 0) z[r] = -INFINITY;
                }
                float pv0 = __builtin_amdgcn_exp2f(z[0]);
                float pv1 = __builtin_amdgcn_exp2f(z[1]);
                float pv2 = __builtin_amdgcn_exp2f(z[2]);
                float pv3 = __builtin_amdgcn_exp2f(z[3]);
                lr[qs] += (pv0 + pv1) + (pv2 + pv3);
                uint2 w = make_uint2(pk2bf(pv0, pv1), pk2bf(pv2, pv3));
                const int rq = qs * 16 + l15;
                const int cq = mt * 2 + (quad >> 1);
                *(uint2*)&Pw[rq * 64 + ((cq ^ (rq & 7)) << 3) + (quad & 1) * 4] = w;
            }
        }

        // PV: A = P (m=q, k=key), B = V rows (k=key, n=dh)
        short8 ap[2][2];
        #pragma unroll
        for (int ms = 0; ms < 2; ++ms) {
            const int rq = ms * 16 + l15;
            ap[ms][0] = *(const short8*)&Pw[rq * 64 + (((    quad) ^ (rq & 7)) << 3)];
            ap[ms][1] = *(const short8*)&Pw[rq * 64 + (((4 + quad) ^ (rq & 7)) << 3)];
        }
        #pragma unroll
        for (int nt = 0; nt < 4; ++nt) {
            const int rv = nt * 16 + l15;
            short8 b0 = *(const short8*)&Vs[rv * 64 + (((    quad) ^ (rv & 7)) << 3)];
            short8 b1 = *(const short8*)&Vs[rv * 64 + (((4 + quad) ^ (rv & 7)) << 3)];
            #pragma unroll
            for (int ms = 0; ms < 2; ++ms) {
                Oa[ms][nt] = __builtin_amdgcn_mfma_f32_16x16x32_bf16(ap[ms][0], b0, Oa[ms][nt], 0, 0, 0);
                Oa[ms][nt] = __builtin_amdgcn_mfma_f32_16x16x32_bf16(ap[ms][1], b1, Oa[ms][nt], 0, 0, 0);
            }
        }
        __syncthreads();

        kptr += 64 * 64;
        vptr += 64;
    }

    // final l reduce across quads, then normalize + write O (bf16 head-major)
    float inv[2];
    #pragma unroll
    for (int qs = 0; qs < 2; ++qs) {
        float l = lr[qs];
        l += __shfl_xor(l, 16);
        l += __shfl_xor(l, 32);
        inv[qs] = 1.f / l;
    }
    unsigned short* obase = Ob + ((size_t)bgh * Nn + q0 + wv * 32) * 64;
    #pragma unroll
    for (int ms = 0; ms < 2; ++ms) {
        #pragma unroll
        for (int r = 0; r < 4; ++r) {
            const float iv = __shfl(inv[ms], quad * 4 + r);
            #pragma unroll
            for (int nt = 0; nt < 4; ++nt)
                obase[(ms * 16 + quad * 4 + r) * 64 + nt * 16 + l15] =
                    f2bf(Oa[ms][nt][r] * iv);
        }
    }
}

// ---------------------------------------------------------------------------
// Kernel 3: bf16 MFMA output projection (verified R5 structure).
// ---------------------------------------------------------------------------
__global__ __launch_bounds__(256) void out_proj(const char* __restrict__ wsb,
                                                float* __restrict__ out)
{
    __shared__ alignas(16) unsigned short As[128 * 64];
    __shared__ alignas(16) unsigned short Bs[128 * 64];

    const int g  = blockIdx.z;
    const int m0 = blockIdx.x * 128;
    const int c0 = blockIdx.y * 128;
    const int tid = threadIdx.x;
    const int wv = tid >> 6, ln = tid & 63;
    const int l15 = ln & 15, quad = ln >> 4;
    const int wm = (wv & 1) * 64, we = (wv >> 1) * 64;

    const unsigned short* Ob = (const unsigned short*)(wsb + OB_B);
    const unsigned short* Wo = (const unsigned short*)(wsb + WO_B);

    const int bq = m0 >> 11;
    const int n0 = m0 & 2047;

    float4v acc[4][4];
    #pragma unroll
    for (int i = 0; i < 4; ++i)
        #pragma unroll
        for (int j = 0; j < 4; ++j) acc[i][j] = (float4v){0.f,0.f,0.f,0.f};

    for (int k0 = 0; k0 < 512; k0 += 64) {
        const int h = k0 >> 6;
        const unsigned short* abase =
            Ob + (((size_t)(bq * Gn + g) * Hn + h) * Nn + n0) * 64;
        const unsigned short* bbase =
            Wo + ((size_t)g * 512 + c0) * 512 + k0;
        #pragma unroll
        for (int it = 0; it < 4; ++it) {
            const int sb  = it * 256 + wv * 64;
            const int slot = sb + ln;
            const int row = slot >> 3;
            const int c8  = (slot & 7) ^ (row & 7);
            gload16(abase + (size_t)row * 64  + c8 * 8, &As[(size_t)sb * 8]);
            gload16(bbase + (size_t)row * 512 + c8 * 8, &Bs[(size_t)sb * 8]);
        }
        __syncthreads();

        #pragma unroll
        for (int kh = 0; kh < 2; ++kh) {
            short8 af[4], bf[4];
            #pragma unroll
            for (int mi = 0; mi < 4; ++mi) {
                const int r = wm + mi * 16 + l15;
                af[mi] = *(const short8*)&As[r * 64 + (((kh*4+quad) ^ (r & 7)) << 3)];
            }
            #pragma unroll
            for (int ni = 0; ni < 4; ++ni) {
                const int r = we + ni * 16 + l15;
                bf[ni] = *(const short8*)&Bs[r * 64 + (((kh*4+quad) ^ (r & 7)) << 3)];
            }
            #pragma unroll
            for (int mi = 0; mi < 4; ++mi)
                #pragma unroll
                for (int ni = 0; ni < 4; ++ni)
                    acc[mi][ni] = __builtin_amdgcn_mfma_f32_16x16x32_bf16(
                        af[mi], bf[ni], acc[mi][ni], 0, 0, 0);
        }
        __syncthreads();
    }

    #pragma unroll
    for (int mi = 0; mi < 4; ++mi) {
        #pragma unroll
        for (int r = 0; r < 4; ++r) {
            const int n = n0 + wm + mi * 16 + quad * 4 + r;
            float* orow = out + ((size_t)(bq * Gn + g) * Nn + n) * Dn;
            #pragma unroll
            for (int ni = 0; ni < 4; ++ni)
                orow[c0 + we + ni * 16 + l15] = acc[mi][ni][r];
        }
    }
}

// ---------------------------------------------------------------------------
extern "C" void kernel_launch(void* const* d_in, const int* in_sizes, int n_in,
                              void* d_out, int out_size, void* d_ws, size_t ws_size,
                              hipStream_t stream)
{
    const float* x     = (const float*)d_in[0];
    const float* Wq    = (const float*)d_in[1];
    const float* Wkv   = (const float*)d_in[2];
    const float* Wout  = (const float*)d_in[3];
    const float* nkv   = (const float*)d_in[4];
    const float* rot_q = (const float*)d_in[5];
    const float* rot_k = (const float*)d_in[6];
    float* out = (float*)d_out;
    char* wsb  = (char*)d_ws;   // needs ~87 MB

    prep<<<dim3(PREP_BLOCKS), 256, 0, stream>>>(x, Wq, Wkv, Wout, nkv,
                                                rot_q, rot_k, wsb);

    qkv_proj<<<dim3(64, 12, 2), 256, 0, stream>>>(wsb);

    attn<<<dim3(BGH * 16), 256, 0, stream>>>((const unsigned short*)(wsb + QB_B),
                                             (const unsigned short*)(wsb + KB_B),
                                             (const unsigned short*)(wsb + VT_B),
                                             (unsigned short*)(wsb + OB_B));

    out_proj<<<dim3(64, 4, 2), 256, 0, stream>>>(wsb, out);
}